// Round 11
// baseline (5351.468 us; speedup 1.0000x reference)
//
#include <hip/hip_runtime.h>

#define DIMD 256
#define SEQT 1024
#define NB   4
#define RBS  36   // 32-row block + 4 pad: conflict-free staggered k/q tiles (R9-verified, 0 conflicts)

typedef float v2f __attribute__((ext_vector_type(2)));
#define FMA2(a,b,c) __builtin_elementwise_fma((a),(b),(c))

__device__ __forceinline__ float sigmoidf_(float x){ return 1.0f/(1.0f+expf(-x)); }

// ---------------------------------------------------------------------------
// GEMM: C[m][n] = sum_k A[m][k] * B[n][k], K = 256 fixed, tiles 64x64.
// EPI==1: C *= sigmoid(gpre[m*N+n])
// ---------------------------------------------------------------------------
template<int EPI>
__global__ __launch_bounds__(256) void gemm_bt(const float* __restrict__ A,
    const float* __restrict__ Bm, float* __restrict__ C, int N,
    const float* __restrict__ gpre)
{
  __shared__ float sA[64][68];
  __shared__ float sB[64][68];
  const int nb = N >> 6;
  const int bm = blockIdx.x / nb, bn = blockIdx.x - bm*nb;
  const int m0 = bm << 6, n0 = bn << 6;
  const int tid = threadIdx.x;
  const int tr = tid >> 4, tc = tid & 15;
  float acc[4][4];
  #pragma unroll
  for (int i=0;i<4;i++)
    #pragma unroll
    for (int j=0;j<4;j++) acc[i][j]=0.f;

  for (int kc=0;kc<4;kc++){
    __syncthreads();
    for (int i=tid;i<1024;i+=256){
      int r = i >> 4, q4 = i & 15;
      *(float4*)&sA[r][q4*4] = ((const float4*)(A  + (m0+r)*256 + kc*64))[q4];
      *(float4*)&sB[r][q4*4] = ((const float4*)(Bm + (n0+r)*256 + kc*64))[q4];
    }
    __syncthreads();
    #pragma unroll
    for (int kq=0;kq<16;kq++){
      float4 av[4], bv[4];
      #pragma unroll
      for (int i=0;i<4;i++) av[i] = *(const float4*)&sA[tr+16*i][kq*4];
      #pragma unroll
      for (int j=0;j<4;j++) bv[j] = *(const float4*)&sB[tc+16*j][kq*4];
      #pragma unroll
      for (int i=0;i<4;i++)
        #pragma unroll
        for (int j=0;j<4;j++)
          acc[i][j] = fmaf(av[i].x,bv[j].x, fmaf(av[i].y,bv[j].y,
                      fmaf(av[i].z,bv[j].z, fmaf(av[i].w,bv[j].w, acc[i][j]))));
    }
  }
  #pragma unroll
  for (int i=0;i<4;i++){
    #pragma unroll
    for (int j=0;j<4;j++){
      int m = m0 + tr + 16*i, n = n0 + tc + 16*j;
      float val = acc[i][j];
      if (EPI==1) val *= sigmoidf_(gpre[m*N+n]);
      C[m*N+n] = val;
    }
  }
}

// ---------------------------------------------------------------------------
// prep: causal dwconv(4) + RoPE + l2norm for q,k ; conv for v ; eta/alpha.
// ---------------------------------------------------------------------------
__global__ __launch_bounds__(256) void prep_kernel(
    const float* __restrict__ qkvr, const float* __restrict__ x,
    const float* __restrict__ cosT, const float* __restrict__ sinT,
    const float* __restrict__ qw, const float* __restrict__ qbias,
    const float* __restrict__ kw, const float* __restrict__ kbias,
    const float* __restrict__ vw, const float* __restrict__ vbias,
    const float* __restrict__ Wparam, const float* __restrict__ bparam,
    float* __restrict__ qo, float* __restrict__ ko, float* __restrict__ vo,
    float* __restrict__ eo, float* __restrict__ ao)
{
  const int bt = blockIdx.x;
  const int t = bt & 1023;
  const int d = threadIdx.x;

  float4 wq = ((const float4*)qw)[d];
  float4 wk = ((const float4*)kw)[d];
  float4 wv = ((const float4*)vw)[d];
  const float wqj[4] = {wq.x,wq.y,wq.z,wq.w};
  const float wkj[4] = {wk.x,wk.y,wk.z,wk.w};
  const float wvj[4] = {wv.x,wv.y,wv.z,wv.w};
  float qa = qbias[d], ka = kbias[d], va = vbias[d];
  #pragma unroll
  for (int j=0;j<4;j++){
    int tt = t - 3 + j;
    if (tt >= 0) {
      const float* row = qkvr + (size_t)(bt - 3 + j) * 768;
      qa = fmaf(row[d],      wqj[j], qa);
      ka = fmaf(row[256+d],  wkj[j], ka);
      va = fmaf(row[512+d],  wvj[j], va);
    }
  }
  vo[bt*256 + d] = va;

  __shared__ float sq[256], sk[256];
  __shared__ float red[4][4];
  sq[d] = qa; sk[d] = ka;
  __syncthreads();
  const int i = d >> 1;
  const float c = cosT[t*128 + i], s = sinT[t*128 + i];
  float qr, krp;
  if ((d & 1) == 0) { qr = sq[d]*c - sq[d+1]*s;  krp = sk[d]*c - sk[d+1]*s; }
  else              { qr = sq[d-1]*s + sq[d]*c;  krp = sk[d-1]*s + sk[d]*c; }

  const float xd = x[bt*256 + d];
  float r0 = qr*qr, r1 = krp*krp, r2 = xd*Wparam[d], r3 = xd*Wparam[256+d];
  #pragma unroll
  for (int m=1;m<64;m<<=1){
    r0 += __shfl_xor(r0, m, 64);
    r1 += __shfl_xor(r1, m, 64);
    r2 += __shfl_xor(r2, m, 64);
    r3 += __shfl_xor(r3, m, 64);
  }
  const int w = d >> 6;
  if ((d & 63) == 0){ red[w][0]=r0; red[w][1]=r1; red[w][2]=r2; red[w][3]=r3; }
  __syncthreads();
  float qss = red[0][0]+red[1][0]+red[2][0]+red[3][0];
  float kss = red[0][1]+red[1][1]+red[2][1]+red[3][1];
  qo[bt*256+d] = qr  / fmaxf(sqrtf(qss), 1e-12f);
  ko[bt*256+d] = krp / fmaxf(sqrtf(kss), 1e-12f);
  if (d == 0){
    float p0 = red[0][2]+red[1][2]+red[2][2]+red[3][2] + bparam[0];
    float p1 = red[0][3]+red[1][3]+red[2][3]+red[3][3] + bparam[1];
    eo[bt] = 1.f/(1.f+expf(-p0));
    ao[bt] = 1.f/(1.f+expf(-p1));
  }
}

// ---------------------------------------------------------------------------
// scan: TWO blocks per batch (8 blocks, one per CU), 1024 threads, one
// barrier/step. Block h owns columns h*128..h*128+127. The only cross-block
// quantity is the scalar sumA^4 (consumed one step later). LEAN SYNC:
// all 32 waves of a batch atomicAdd their wave-reduced partial directly
// into one global slot (fire-and-forget, no LDS stage, no release STORE),
// then one RELEASE fetch_add on a counter; consumers spin-ACQUIRE until
// counter==32. Publish fires right after the 6-shuffle s4 reduce; consume
// happens after next barrier + prefetch issue -> slack covers L2 latency.
// amdgpu_waves_per_eu(4,4): exactly one block/CU (true: grid=8) -> 128-reg
// budget/wave, giving the allocator room to keep A in arch VGPRs (A=32
// floats + ~20 working), which VOP3P packed math requires.
// ---------------------------------------------------------------------------
__global__ void __attribute__((amdgpu_flat_work_group_size(1024,1024),
                               amdgpu_waves_per_eu(4,4)))
scan_kernel(
    const float* __restrict__ qn, const float* __restrict__ kn,
    const float* __restrict__ vn, const float* __restrict__ eta,
    const float* __restrict__ alpha, const float* __restrict__ W0,
    float* __restrict__ y, float* __restrict__ g_sum,
    unsigned* __restrict__ g_cnt)
{
  const int blkid = blockIdx.x;       // 0..7
  const int b     = blkid >> 1;
  const int h     = blkid & 1;
  const int tid = threadIdx.x;
  const int rg = tid & 7;             // 8 row groups x 32 rows
  const int cl = tid >> 3;            // local column 0..127
  const int cg = (h << 7) + cl;       // global column
  const int r0 = rg << 5;
  const int koff = rg * RBS;

  __shared__ float s_k[3][8*RBS], s_q[3][8*RBS], s_v[3][256];
  __shared__ float s_ea[3][2];

  // A2[2j]={A[r0+4j][cg],A[r0+4j+1][cg]}, A2[2j+1]={+2,+3}, j=0..7
  v2f A2[16];
  #pragma unroll
  for (int j=0;j<16;j++) A2[j] = (v2f)(0.f);

  const float* kb = kn + b*SEQT*DIMD;
  const float* qb = qn + b*SEQT*DIMD;
  const float* vb = vn + b*SEQT*DIMD;
  const float* eb = eta   + b*SEQT;
  const float* ab = alpha + b*SEQT;
  float* yb = y + b*SEQT*DIMD;
  float*    sumb = g_sum + b*SEQT;
  unsigned* cntb = g_cnt + b*SEQT;

  // ---- prologue: stage t=0 -> buf0 (staggered k/q) ; load t=1 into pf
  if (tid < 64) {
    float4 v0 = ((const float4*)kb)[tid];
    *(float4*)&s_k[0][(tid>>3)*RBS + (tid&7)*4] = v0;
  } else if (tid < 128) {
    int i = tid-64;
    float4 v0 = ((const float4*)qb)[i];
    *(float4*)&s_q[0][(i>>3)*RBS + (i&7)*4] = v0;
  } else if (tid < 192) {
    ((float4*)s_v[0])[tid-128] = ((const float4*)vb)[tid-128];
  }
  if (tid == 192) { s_ea[0][0] = eb[0]; s_ea[0][1] = ab[0]; }

  float4 pf = make_float4(0.f,0.f,0.f,0.f);
  float pe = 0.f, pa = 0.f;
  if (tid < 64)       pf = ((const float4*)(kb + DIMD))[tid];
  else if (tid < 128) pf = ((const float4*)(qb + DIMD))[tid-64];
  else if (tid < 192) pf = ((const float4*)(vb + DIMD))[tid-128];
  if (tid == 192) { pe = eb[1]; pa = ab[1]; }
  __syncthreads();

  // ---- prologue: pred_raw(0) = k(0) . W0 over own rows, own column
  float pr = 0.f;
  {
    #pragma unroll 4
    for (int j=0;j<32;j++)
      pr = fmaf(s_k[0][koff + j], W0[(size_t)(r0+j)*DIMD + cg], pr);
    pr += __shfl_xor(pr, 1, 64);
    pr += __shfl_xor(pr, 2, 64);
    pr += __shfl_xor(pr, 4, 64);
  }

  float up = 0.f;
  int cur = 0;

  for (int t=0; t<SEQT; ++t) {
    const int nxt = (cur==2) ? 0 : cur+1;

    // ---- stage pf (t+1) -> buf nxt
    if (t+1 < SEQT) {
      if (tid < 64)       *(float4*)&s_k[nxt][(tid>>3)*RBS + (tid&7)*4] = pf;
      else if (tid < 128){ int i = tid-64; *(float4*)&s_q[nxt][(i>>3)*RBS + (i&7)*4] = pf; }
      else if (tid < 192) ((float4*)s_v[nxt])[tid-128] = pf;
      if (tid == 192) { s_ea[nxt][0]=pe; s_ea[nxt][1]=pa; }
    }

    __syncthreads();                               // the ONE barrier

    // ---- issue global prefetch for t+2
    if (t+2 < SEQT) {
      if (tid < 64)       pf = ((const float4*)(kb + (t+2)*DIMD))[tid];
      else if (tid < 128) pf = ((const float4*)(qb + (t+2)*DIMD))[tid-64];
      else if (tid < 192) pf = ((const float4*)(vb + (t+2)*DIMD))[tid-128];
      if (tid == 192) { pe = eb[t+2]; pa = ab[t+2]; }
    }

    // ---- inv(t-1): spin-acquire on the batch counter, then read the sum
    float scale = 1.f;
    if (t > 0) {
      while (__hip_atomic_load(&cntb[t-1], __ATOMIC_ACQUIRE,
                               __HIP_MEMORY_SCOPE_AGENT) != 32u) {}
      float s4t = sumb[t-1];
      float w = sqrtf(s4t) + 1e-6f;
      float r = __builtin_amdgcn_rcpf(w);
      r = r * (2.f - w*r);          // Newton: feeds the recurrence
      scale = r;
      if (rg == 0) yb[(size_t)(t-1)*DIMD + cg] = up * r;
    }

    // ---- t0 for own column
    const float et = s_ea[cur][0], al = s_ea[cur][1];
    float pred = pr * scale;
    float df = pred - s_v[cur][cg];
    float e  = __expf(20.f*df);                    // tanh(10df)=1-2/(e+1)
    float th = 1.f - 2.f*__builtin_amdgcn_rcpf(e + 1.f);
    float t0 = et * 3.f * th * (df*df);
    v2f nt0; nt0.x = -t0; nt0.y = -t0;
    v2f alv; alv.x = al;  alv.y = al;

    // ---- fused: A update + sumA^4 + q-dot + NEXT k-dot (one pass)
    const float4* kp = (const float4*)(s_k[cur] + koff);
    const float4* qp = (const float4*)(s_q[cur] + koff);
    const float4* np = (const float4*)(s_k[nxt] + koff);   // k(t+1)
    v2f s4v = (v2f)(0.f), uv = (v2f)(0.f), pv2 = (v2f)(0.f);
    #pragma unroll
    for (int j=0;j<8;j++){
      float4 k4 = kp[j], q4 = qp[j], n4 = np[j];
      v2f klo = {k4.x,k4.y}, khi = {k4.z,k4.w};
      v2f qlo = {q4.x,q4.y}, qhi = {q4.z,q4.w};
      v2f nlo = {n4.x,n4.y}, nhi = {n4.z,n4.w};
      v2f a, sq;
      a = FMA2(alv, A2[2*j],   nt0*klo); A2[2*j]   = a;
      sq = a*a; s4v = FMA2(sq, sq, s4v);
      uv  = FMA2(qlo, a, uv);
      pv2 = FMA2(nlo, a, pv2);
      a = FMA2(alv, A2[2*j+1], nt0*khi); A2[2*j+1] = a;
      sq = a*a; s4v = FMA2(sq, sq, s4v);
      uv  = FMA2(qhi, a, uv);
      pv2 = FMA2(nhi, a, pv2);
    }

    // ---- s4: wave reduce then publish (fire-and-forget + release count)
    float s4 = s4v.x + s4v.y;
    #pragma unroll
    for (int m=1;m<64;m<<=1) s4 += __shfl_xor(s4, m, 64);
    if ((tid & 63) == 0) {
      atomicAdd(&sumb[t], s4);                         // device-scope, no return
      __hip_atomic_fetch_add(&cntb[t], 1u,
                             __ATOMIC_RELEASE, __HIP_MEMORY_SCOPE_AGENT);
    }

    // ---- cross-rg reduces (8 adjacent lanes share the column)
    float u = uv.x + uv.y;
    float p = pv2.x + pv2.y;
    u += __shfl_xor(u, 1, 64); p += __shfl_xor(p, 1, 64);
    u += __shfl_xor(u, 2, 64); p += __shfl_xor(p, 2, 64);
    u += __shfl_xor(u, 4, 64); p += __shfl_xor(p, 4, 64);
    up = u; pr = p;

    cur = nxt;
  }

  // epilogue: y for t = 1023
  {
    while (__hip_atomic_load(&cntb[SEQT-1], __ATOMIC_ACQUIRE,
                             __HIP_MEMORY_SCOPE_AGENT) != 32u) {}
    float s4t = sumb[SEQT-1];
    float w = sqrtf(s4t) + 1e-6f;
    float r = __builtin_amdgcn_rcpf(w);
    r = r * (2.f - w*r);
    if (rg == 0) yb[(size_t)(SEQT-1)*DIMD + cg] = up * r;
  }
}

// ---------------------------------------------------------------------------
extern "C" void kernel_launch(void* const* d_in, const int* in_sizes, int n_in,
                              void* d_out, int out_size, void* d_ws, size_t ws_size,
                              hipStream_t stream)
{
  const float* x     = (const float*)d_in[0];
  const float* cosT  = (const float*)d_in[1];
  const float* sinT  = (const float*)d_in[2];
  const float* Wqkv  = (const float*)d_in[3];
  const float* qw    = (const float*)d_in[4];
  const float* qb    = (const float*)d_in[5];
  const float* kw    = (const float*)d_in[6];
  const float* kb    = (const float*)d_in[7];
  const float* vw    = (const float*)d_in[8];
  const float* vb    = (const float*)d_in[9];
  const float* Wparam= (const float*)d_in[10];
  const float* bparam= (const float*)d_in[11];
  const float* W0    = (const float*)d_in[12];
  const float* Wgate = (const float*)d_in[13];
  const float* Wout  = (const float*)d_in[14];
  float* out = (float*)d_out;

  float* ws    = (float*)d_ws;
  float* qkvr  = ws;                         // 4*1024*768  = 3,145,728 f
  float* qn    = qkvr + 4*1024*768;          // 1,048,576 f
  float* kn    = qn   + 4*1024*256;
  float* vn    = kn   + 4*1024*256;
  float* eta   = vn   + 4*1024*256;          // 4096 f
  float* alpha = eta  + 4096;                // 4096 f
  // qkvr is dead after prep_kernel -> reuse its space:
  float* yv    = qkvr;                       // scan output   (1,048,576 f)
  float* tmpg  = qkvr + 1048576;             // gate preact   (1,048,576 f)
  float* g_sum = qkvr + 2097152;             // s4 sums       (4096 f)
  unsigned* g_cnt = (unsigned*)(qkvr + 2097152 + 4096);   // counters (4096 u32)

  // 1) qkv = x @ Wqkv.T          (4096 x 768)
  gemm_bt<0><<<dim3(64*12), 256, 0, stream>>>(x, Wqkv, qkvr, 768, nullptr);
  // 2) conv + rope + l2norm + eta/alpha   (qkvr consumed here)
  prep_kernel<<<dim3(4096), 256, 0, stream>>>(qkvr, x, cosT, sinT,
      qw, qb, kw, kb, vw, vb, Wparam, bparam, qn, kn, vn, eta, alpha);
  // 2b) zero the s4 sums + counters (ordered before scan on the stream)
  hipMemsetAsync(g_sum, 0, (size_t)8192*sizeof(float), stream);
  // 3) the sequential scan: 2 blocks per batch, lean cross-block s4 exchange
  scan_kernel<<<dim3(NB*2), 1024, 0, stream>>>(qn, kn, vn, eta, alpha, W0,
                                               yv, g_sum, g_cnt);
  // 4) gate preact = x @ Wgate.T (4096 x 256)
  gemm_bt<0><<<dim3(64*4), 256, 0, stream>>>(x, Wgate, tmpg, 256, nullptr);
  // 5) out = (y @ Wout.T) * sigmoid(gate)
  gemm_bt<1><<<dim3(64*4), 256, 0, stream>>>(yv, Wout, out, 256, tmpg);
}